// Round 19
// baseline (58.477 us; speedup 1.0000x reference)
//
#include <hip/hip_runtime.h>
#include <hip/hip_bf16.h>

// SCE loss: loss = mean_e [ logsumexp_j(parts[e].centers[j]) - parts[e].centers[e] ]
// K=16384, D=128, fp32 inputs, scalar fp32 output.
//
//  k1: fp32 -> fp8(e4m3) convert + fused fp32 diagonal dot. parts -> pb8
//      [K][128] (scaled by log2 e); centers -> cb8 [K][128]; both row-major.
//  k2: sum-of-exp2 GEMM with MX-scaled FP8 MFMA (unit scales),
//      mfma_scale_f32_32x32x64_f8f6f4 (R17: 69->45us).
//      R19: R17 structure exactly (single acc pair — R18's X/Y pipeline
//      spilled, WRITE 36MB), but __launch_bounds__(256,5): the fp8 kernel
//      uses ~52 arch + 32 unified-acc ~= 84 regs < (256,5)'s ~102 budget
//      (the bf16 version needed ~96 and spilled at 5 waves; fp8 fits).
//      +25% TLP against the serial-chain stall (all pipes <=43% busy).
//      A-tile 4KB in LDS (XOR-swizzled), 2-tile rounds, 1 barrier/round.
//  k3: finalize: 1 thread/row: sum 32 split partials + rowdot -> rowloss;
//      LDS-reduce -> 64 block partials (no atomics).
//  k4: reduce 64 partials -> mean.

#define K_DIM 16384
#define D_DIM 128
#define NSPLIT 32
#define COLS_PER_SPLIT (K_DIM / NSPLIT)          // 512
#define TILES_PER_SPLIT (COLS_PER_SPLIT / 32)    // 16
#define NROUND (TILES_PER_SPLIT / 2)             // 8

typedef __attribute__((ext_vector_type(8)))  int    i32x8;
typedef __attribute__((ext_vector_type(16))) float  f32x16;
typedef __attribute__((ext_vector_type(4)))  float  f32x4;
typedef __attribute__((ext_vector_type(2)))  float  f32x2;

__device__ __forceinline__ unsigned pack_fp8x4(float f0, float f1, float f2, float f3) {
    int r = 0;
    r = __builtin_amdgcn_cvt_pk_fp8_f32(f0, f1, r, false);  // bytes 0,1
    r = __builtin_amdgcn_cvt_pk_fp8_f32(f2, f3, r, true);   // bytes 2,3
    return (unsigned)r;
}

__global__ void convert_kernel(const float* __restrict__ parts,
                               const float* __restrict__ centers,
                               unsigned* __restrict__ pb8,    // [K][128] fp8 as u32[K*32]
                               unsigned* __restrict__ cb8,    // [K][128] fp8 as u32[K*32]
                               float* __restrict__ rowdot) {  // [K]
    const float LOG2E = 1.4426950408889634f;
    int i = blockIdx.x * blockDim.x + threadIdx.x;   // one thread per 4 elems
    const int lane = threadIdx.x & 63;

    f32x4 p = reinterpret_cast<const f32x4*>(parts)[i];
    f32x4 c = reinterpret_cast<const f32x4*>(centers)[i];
    pb8[i] = pack_fp8x4(p[0] * LOG2E, p[1] * LOG2E, p[2] * LOG2E, p[3] * LOG2E);
    cb8[i] = pack_fp8x4(c[0], c[1], c[2], c[3]);

    // fused fp32 diagonal dot: 32 consecutive threads own one row
    const int j = (i * 4) >> 7;
    float dd = p[0] * c[0] + p[1] * c[1] + p[2] * c[2] + p[3] * c[3];
#pragma unroll
    for (int off = 16; off > 0; off >>= 1)
        dd += __shfl_xor(dd, off);       // stays within each 32-lane half
    if ((lane & 31) == 0)
        rowdot[j] = dd;
}

// Partial sum-of-exp2 (base-2). One wave: 64 e-rows x one split.
// MX-fp8 MFMA; A-tiles (4KB) staged in LDS, XOR-swizzled; 2-tile rounds.
__launch_bounds__(256, 5)
__global__ void lse_gemm_kernel(const unsigned char* __restrict__ P8,  // pb8 [K][128]
                                const unsigned char* __restrict__ C8,  // cb8 [K][128]
                                float* __restrict__ Sout) {            // [K][NSPLIT]
    // 2 pairs x 2 tiles x 4KB
    __shared__ __attribute__((aligned(128))) unsigned char As[2][2][4096];

    const int bid   = blockIdx.x;                 // 2048 blocks
    const int xcd    = bid & 7;                   // XCD-aware remap
    const int k      = bid >> 3;
    const int split  = xcd * 4 + (k & 3);
    const int rowblk = k >> 2;
    const int tid   = threadIdx.x;
    const int lane  = tid & 63;
    const int w     = tid >> 6;
    const int l31   = lane & 31;
    const int hi    = lane >> 5;
    const int rowgrp = rowblk * 4 + w;            // 0..255
    const int e0    = rowgrp * 64;
    const int e_lo  = e0 + l31;
    const int e_hi  = e0 + 32 + l31;

    // B fragments: lane holds 32 K-bytes (hi*32..hi*32+31) per K=64 chunk.
    i32x8 bl0, bl1, bh0, bh1;
    {
        const unsigned char* plo = P8 + (size_t)e_lo * D_DIM + hi * 32;
        const unsigned char* phi = P8 + (size_t)e_hi * D_DIM + hi * 32;
#pragma unroll
        for (int q = 0; q < 4; ++q) {
            bl0[q]     = reinterpret_cast<const int*>(plo)[q];
            bl1[q]     = reinterpret_cast<const int*>(plo + 64)[q];
            bh0[q]     = reinterpret_cast<const int*>(phi)[q];
            bh1[q]     = reinterpret_cast<const int*>(phi + 64)[q];
            bl0[q + 4] = reinterpret_cast<const int*>(plo + 16)[q];
            bl1[q + 4] = reinterpret_cast<const int*>(plo + 80)[q];
            bh0[q + 4] = reinterpret_cast<const int*>(phi + 16)[q];
            bh1[q + 4] = reinterpret_cast<const int*>(phi + 80)[q];
        }
    }

    const int j0 = split * COLS_PER_SPLIT;
    // Staging: thread tid covers 16B: row j_w=tid>>3, col d_w=(tid&7)*16.
    const int j_w = tid >> 3;
    const int d_w = (tid & 7) * 16;
    const unsigned char* gsrc = C8 + (size_t)(j0 + j_w) * D_DIM + d_w;
    const int woff = j_w * 128 + (d_w ^ ((j_w & 7) << 4));   // swizzled LDS dest

    // A-read offsets (swizzled), lane (l31,hi): 2x16B per K=64 chunk
    const int swz = (l31 & 7) << 4;
    const int rbase = l31 * 128;
    const int rk0a = rbase + (((hi * 32))      ^ swz);
    const int rk0b = rbase + (((hi * 32) + 16) ^ swz);
    const int rk1a = rbase + (((64 + hi * 32))      ^ swz);
    const int rk1b = rbase + (((64 + hi * 32) + 16) ^ swz);

    const f32x16 zc = {};
    float s0 = 0.f, s1 = 0.f;

    auto expsum = [&](const f32x16& acc) -> float {   // f32x2 trees -> pk_add
        f32x2 v0 = {__builtin_amdgcn_exp2f(acc[0]),  __builtin_amdgcn_exp2f(acc[1])};
        f32x2 v1 = {__builtin_amdgcn_exp2f(acc[2]),  __builtin_amdgcn_exp2f(acc[3])};
        f32x2 v2 = {__builtin_amdgcn_exp2f(acc[4]),  __builtin_amdgcn_exp2f(acc[5])};
        f32x2 v3 = {__builtin_amdgcn_exp2f(acc[6]),  __builtin_amdgcn_exp2f(acc[7])};
        f32x2 v4 = {__builtin_amdgcn_exp2f(acc[8]),  __builtin_amdgcn_exp2f(acc[9])};
        f32x2 v5 = {__builtin_amdgcn_exp2f(acc[10]), __builtin_amdgcn_exp2f(acc[11])};
        f32x2 v6 = {__builtin_amdgcn_exp2f(acc[12]), __builtin_amdgcn_exp2f(acc[13])};
        f32x2 v7 = {__builtin_amdgcn_exp2f(acc[14]), __builtin_amdgcn_exp2f(acc[15])};
        v0 += v1; v2 += v3; v4 += v5; v6 += v7;
        v0 += v2; v4 += v6;
        v0 += v4;
        return v0[0] + v0[1];
    };

    auto mfma_tile = [&](const unsigned char* base, f32x16& acc0, f32x16& acc1) {
        i32x8 a0, a1;
#pragma unroll
        for (int q = 0; q < 4; ++q) {
            a0[q]     = reinterpret_cast<const int*>(base + rk0a)[q];
            a0[q + 4] = reinterpret_cast<const int*>(base + rk0b)[q];
            a1[q]     = reinterpret_cast<const int*>(base + rk1a)[q];
            a1[q + 4] = reinterpret_cast<const int*>(base + rk1b)[q];
        }
        acc0 = __builtin_amdgcn_mfma_scale_f32_32x32x64_f8f6f4(
                   a0, bl0, zc,   0, 0, 0, 0x7F, 0, 0x7F);
        acc0 = __builtin_amdgcn_mfma_scale_f32_32x32x64_f8f6f4(
                   a1, bl1, acc0, 0, 0, 0, 0x7F, 0, 0x7F);
        acc1 = __builtin_amdgcn_mfma_scale_f32_32x32x64_f8f6f4(
                   a0, bh0, zc,   0, 0, 0, 0x7F, 0, 0x7F);
        acc1 = __builtin_amdgcn_mfma_scale_f32_32x32x64_f8f6f4(
                   a1, bh1, acc1, 0, 0, 0, 0x7F, 0, 0x7F);
    };

    // prologue: stage tiles 0,1 into pair 0 (16B per thread per tile)
    {
        int4 r0 = *reinterpret_cast<const int4*>(gsrc);
        *reinterpret_cast<int4*>(&As[0][0][woff]) = r0;
        int4 r1 = *reinterpret_cast<const int4*>(gsrc + 32 * D_DIM);
        *reinterpret_cast<int4*>(&As[0][1][woff]) = r1;
    }
    __syncthreads();

    for (int r = 0; r < NROUND; ++r) {
        const int cur = r & 1;
        const int nxt = cur ^ 1;
        const bool pf = (r + 1 < NROUND);
        f32x16 acc0, acc1;

        // ---- tile 2r
        {
            int4 rg;
            if (pf) rg = *reinterpret_cast<const int4*>(gsrc + (size_t)(2 * r + 2) * 32 * D_DIM);
            mfma_tile(&As[cur][0][0], acc0, acc1);
            if (pf) *reinterpret_cast<int4*>(&As[nxt][0][woff]) = rg;
        }
        s0 += expsum(acc0);
        s1 += expsum(acc1);

        // ---- tile 2r+1
        {
            int4 rg;
            if (pf) rg = *reinterpret_cast<const int4*>(gsrc + (size_t)(2 * r + 3) * 32 * D_DIM);
            mfma_tile(&As[cur][1][0], acc0, acc1);
            if (pf) *reinterpret_cast<int4*>(&As[nxt][1][woff]) = rg;
        }
        s0 += expsum(acc0);
        s1 += expsum(acc1);

        __syncthreads();
    }

    // lane and lane+32 hold the same e-rows, disjoint j-quarters -> combine.
    s0 += __shfl_xor(s0, 32);
    s1 += __shfl_xor(s1, 32);

    if (lane < 32) {
        Sout[(size_t)e_lo * NSPLIT + split] = s0;
        Sout[(size_t)e_hi * NSPLIT + split] = s1;
    }
}

// One thread per row: combine split partials -> rowloss; LDS-reduce -> partial.
__global__ void finalize_kernel(const float* __restrict__ Sp,      // [K][NSPLIT]
                                const float* __restrict__ rowdot,  // [K]
                                float* __restrict__ partial) {     // [64]
    __shared__ float sm[256];
    const int row = blockIdx.x * 256 + threadIdx.x;

    const f32x4* sp = reinterpret_cast<const f32x4*>(Sp + (size_t)row * NSPLIT);
    float S = 0.0f;
#pragma unroll
    for (int q = 0; q < NSPLIT / 4; ++q) {
        f32x4 v = sp[q];
        S += (v[0] + v[1]) + (v[2] + v[3]);
    }
    const float LN2 = 0.6931471805599453f;
    float loss = LN2 * __builtin_amdgcn_logf(S) - rowdot[row];  // v_log_f32 = log2

    sm[threadIdx.x] = loss;
    __syncthreads();
    for (int off = 128; off > 0; off >>= 1) {
        if (threadIdx.x < off) sm[threadIdx.x] += sm[threadIdx.x + off];
        __syncthreads();
    }
    if (threadIdx.x == 0)
        partial[blockIdx.x] = sm[0];
}

__global__ void reduce_kernel(const float* __restrict__ partial, float* __restrict__ out) {
    const int lane = threadIdx.x;   // 64 threads
    float v = partial[lane];
#pragma unroll
    for (int off = 32; off > 0; off >>= 1)
        v += __shfl_xor(v, off);
    if (lane == 0)
        out[0] = v / (float)K_DIM;
}

extern "C" void kernel_launch(void* const* d_in, const int* in_sizes, int n_in,
                              void* d_out, int out_size, void* d_ws, size_t ws_size,
                              hipStream_t stream) {
    const float* parts   = (const float*)d_in[0];
    const float* centers = (const float*)d_in[1];
    float* out = (float*)d_out;

    char* ws = (char*)d_ws;
    unsigned* pb8 = (unsigned*)ws;                             // 2 MB
    unsigned* cb8 = (unsigned*)(ws + 2u * 1024 * 1024);        // 2 MB
    float*  Sp  = (float*)(ws + 4u * 1024 * 1024);             // 2 MB (K*32 f32)
    float*  rowdot  = Sp + (size_t)K_DIM * NSPLIT;             // 64 KB
    float*  partial = rowdot + K_DIM;                          // 256 B

    const int n4 = (K_DIM * D_DIM) / 4;
    convert_kernel<<<n4 / 256, 256, 0, stream>>>(parts, centers, pb8, cb8, rowdot);
    lse_gemm_kernel<<<(K_DIM / 256) * NSPLIT, 256, 0, stream>>>(
        (const unsigned char*)pb8, (const unsigned char*)cb8, Sp);
    finalize_kernel<<<K_DIM / 256, 256, 0, stream>>>(Sp, rowdot, partial);
    reduce_kernel<<<1, 64, 0, stream>>>(partial, out);
}

// Round 20
// 55.389 us; speedup vs baseline: 1.0558x; 1.0558x over previous
//
#include <hip/hip_runtime.h>
#include <hip/hip_bf16.h>

// SCE loss: loss = mean_e [ logsumexp_j(parts[e].centers[j]) - parts[e].centers[e] ]
// K=16384, D=128, fp32 inputs, scalar fp32 output.
//
//  k1: fp32 -> fp8(e4m3) convert + fused fp32 diagonal dot. parts -> pb8
//      [K][128] row-major (scaled by log2 e); centers -> cbI8 fragment-
//      interleaved [K/16][4][16][32] so LDS A-reads are lane-contiguous.
//  k2: sum-of-exp2 GEMM, mfma_scale_f32_16x16x128_f8f6f4 (unit scales):
//      ONE instruction = full K=128 (no chain), acc = 4 regs. Per tile:
//      8 independent MFMAs (2 jblocks x 4 eblocks), each with its own
//      4-wide exp tree -> wide shallow dep graph, trans/matrix overlap
//      WITHOUT extra acc registers (R18's X/Y 32-reg approach spilled;
//      R19's (256,5) spilled -> occupancy hard-capped at (256,4)).
//      A-tile 4KB in LDS, lane-contiguous reads (no swizzle, ~0 conflicts
//      vs R17's 2.1M). 2-tile rounds, 1 barrier/round.
//  k3: finalize: 1 thread/row: sum 32 split partials + rowdot -> rowloss;
//      LDS-reduce -> 64 block partials (no atomics).
//  k4: reduce 64 partials -> mean.

#define K_DIM 16384
#define D_DIM 128
#define NSPLIT 32
#define COLS_PER_SPLIT (K_DIM / NSPLIT)          // 512
#define TILES_PER_SPLIT (COLS_PER_SPLIT / 32)    // 16
#define NROUND (TILES_PER_SPLIT / 2)             // 8

typedef __attribute__((ext_vector_type(8)))  int    i32x8;
typedef __attribute__((ext_vector_type(4)))  float  f32x4;
typedef __attribute__((ext_vector_type(2)))  float  f32x2;

__device__ __forceinline__ unsigned pack_fp8x4(float f0, float f1, float f2, float f3) {
    int r = 0;
    r = __builtin_amdgcn_cvt_pk_fp8_f32(f0, f1, r, false);  // bytes 0,1
    r = __builtin_amdgcn_cvt_pk_fp8_f32(f2, f3, r, true);   // bytes 2,3
    return (unsigned)r;
}

__global__ void convert_kernel(const float* __restrict__ parts,
                               const float* __restrict__ centers,
                               unsigned* __restrict__ pb8,    // [K][128] row-major
                               unsigned* __restrict__ cbI8,   // [K/16][4][16][32]
                               float* __restrict__ rowdot) {  // [K]
    const float LOG2E = 1.4426950408889634f;
    int i = blockIdx.x * blockDim.x + threadIdx.x;   // one thread per 4 elems
    const int lane = threadIdx.x & 63;

    f32x4 p = reinterpret_cast<const f32x4*>(parts)[i];
    f32x4 c = reinterpret_cast<const f32x4*>(centers)[i];
    pb8[i] = pack_fp8x4(p[0] * LOG2E, p[1] * LOG2E, p[2] * LOG2E, p[3] * LOG2E);

    const int e0v = i * 4;
    const int j   = e0v >> 7;        // row
    const int d0  = e0v & 127;       // col
    // cbI8: byte (j,d) -> ((jb*4 + c)*16 + jr)*32 + b ; c=d>>5, b=d&31
    const int idx = (((j >> 4) * 4 + (d0 >> 5)) * 16 + (j & 15)) * 8 + ((d0 & 31) >> 2);
    cbI8[idx] = pack_fp8x4(c[0], c[1], c[2], c[3]);

    // fused fp32 diagonal dot: 32 consecutive threads own one row
    float dd = p[0] * c[0] + p[1] * c[1] + p[2] * c[2] + p[3] * c[3];
#pragma unroll
    for (int off = 16; off > 0; off >>= 1)
        dd += __shfl_xor(dd, off);       // stays within each 32-lane half
    if ((lane & 31) == 0)
        rowdot[j] = dd;
}

// Partial sum-of-exp2 (base-2). One wave: 64 e-rows x one split.
// 16x16x128 MX-fp8 MFMA; A-tiles (4KB) staged in LDS, lane-contiguous.
__launch_bounds__(256, 4)
__global__ void lse_gemm_kernel(const unsigned char* __restrict__ P8,   // pb8 [K][128]
                                const unsigned char* __restrict__ CI8,  // cbI8
                                float* __restrict__ Sout) {             // [K][NSPLIT]
    // 2 pairs x 2 tiles x 4KB
    __shared__ __attribute__((aligned(128))) unsigned char As[2][2][4096];

    const int bid   = blockIdx.x;                 // 2048 blocks
    const int xcd    = bid & 7;                   // XCD-aware remap
    const int k      = bid >> 3;
    const int split  = xcd * 4 + (k & 3);
    const int rowblk = k >> 2;
    const int tid   = threadIdx.x;
    const int lane  = tid & 63;
    const int w     = tid >> 6;
    const int l15   = lane & 15;
    const int lg    = lane >> 4;                  // lane group 0..3
    const int rowgrp = rowblk * 4 + w;            // 0..255
    const int e0    = rowgrp * 64;

    // B fragments (parts rows): eblock eb, lane -> col e0+eb*16+l15,
    // k-bytes lg*32..+31 of that row. 4 x i32x8 = 32 VGPR.
    i32x8 bf[4];
#pragma unroll
    for (int eb = 0; eb < 4; ++eb) {
        const unsigned char* pr = P8 + (size_t)(e0 + eb * 16 + l15) * D_DIM + lg * 32;
#pragma unroll
        for (int q = 0; q < 4; ++q) {
            bf[eb][q]     = reinterpret_cast<const int*>(pr)[q];
            bf[eb][q + 4] = reinterpret_cast<const int*>(pr + 16)[q];
        }
    }

    const int j0 = split * COLS_PER_SPLIT;
    // Staging: thread tid copies 16B, linear (cbI8 tile is 4KB contiguous).
    const unsigned char* gsrc = CI8 + (size_t)(j0 >> 4) * 2048 + tid * 16;
    // A-read offset within a 2KB jblock: lane -> row l15, k-chunk lg.
    const int ra = l15 * 32 + lg * 512;

    const f32x4 zc = {};
    float s0 = 0.f, s1 = 0.f, s2 = 0.f, s3 = 0.f;

    auto esum4 = [&](const f32x4& acc) -> float {
        f32x2 v = {__builtin_amdgcn_exp2f(acc[0]), __builtin_amdgcn_exp2f(acc[1])};
        f32x2 u = {__builtin_amdgcn_exp2f(acc[2]), __builtin_amdgcn_exp2f(acc[3])};
        v += u;
        return v[0] + v[1];
    };

    auto do_tile = [&](const unsigned char* base) {
        i32x8 aA, aB;                 // jblock 0 and 1 fragments
#pragma unroll
        for (int q = 0; q < 4; ++q) {
            aA[q]     = reinterpret_cast<const int*>(base + ra)[q];
            aA[q + 4] = reinterpret_cast<const int*>(base + ra + 16)[q];
            aB[q]     = reinterpret_cast<const int*>(base + 2048 + ra)[q];
            aB[q + 4] = reinterpret_cast<const int*>(base + 2048 + ra + 16)[q];
        }
        f32x4 acc;
        acc = __builtin_amdgcn_mfma_scale_f32_16x16x128_f8f6f4(aA, bf[0], zc, 0, 0, 0, 0x7F, 0, 0x7F);
        s0 += esum4(acc);
        acc = __builtin_amdgcn_mfma_scale_f32_16x16x128_f8f6f4(aB, bf[0], zc, 0, 0, 0, 0x7F, 0, 0x7F);
        s0 += esum4(acc);
        acc = __builtin_amdgcn_mfma_scale_f32_16x16x128_f8f6f4(aA, bf[1], zc, 0, 0, 0, 0x7F, 0, 0x7F);
        s1 += esum4(acc);
        acc = __builtin_amdgcn_mfma_scale_f32_16x16x128_f8f6f4(aB, bf[1], zc, 0, 0, 0, 0x7F, 0, 0x7F);
        s1 += esum4(acc);
        acc = __builtin_amdgcn_mfma_scale_f32_16x16x128_f8f6f4(aA, bf[2], zc, 0, 0, 0, 0x7F, 0, 0x7F);
        s2 += esum4(acc);
        acc = __builtin_amdgcn_mfma_scale_f32_16x16x128_f8f6f4(aB, bf[2], zc, 0, 0, 0, 0x7F, 0, 0x7F);
        s2 += esum4(acc);
        acc = __builtin_amdgcn_mfma_scale_f32_16x16x128_f8f6f4(aA, bf[3], zc, 0, 0, 0, 0x7F, 0, 0x7F);
        s3 += esum4(acc);
        acc = __builtin_amdgcn_mfma_scale_f32_16x16x128_f8f6f4(aB, bf[3], zc, 0, 0, 0, 0x7F, 0, 0x7F);
        s3 += esum4(acc);
    };

    // prologue: stage tiles 0,1 into pair 0 (16B per thread per tile)
    {
        int4 r0 = *reinterpret_cast<const int4*>(gsrc);
        *reinterpret_cast<int4*>(&As[0][0][tid * 16]) = r0;
        int4 r1 = *reinterpret_cast<const int4*>(gsrc + 4096);
        *reinterpret_cast<int4*>(&As[0][1][tid * 16]) = r1;
    }
    __syncthreads();

    for (int r = 0; r < NROUND; ++r) {
        const int cur = r & 1;
        const int nxt = cur ^ 1;
        const bool pf = (r + 1 < NROUND);

        {   // ---- tile 2r
            int4 rg;
            if (pf) rg = *reinterpret_cast<const int4*>(gsrc + (size_t)(2 * r + 2) * 4096);
            do_tile(&As[cur][0][0]);
            if (pf) *reinterpret_cast<int4*>(&As[nxt][0][tid * 16]) = rg;
        }
        {   // ---- tile 2r+1
            int4 rg;
            if (pf) rg = *reinterpret_cast<const int4*>(gsrc + (size_t)(2 * r + 3) * 4096);
            do_tile(&As[cur][1][0]);
            if (pf) *reinterpret_cast<int4*>(&As[nxt][1][tid * 16]) = rg;
        }
        __syncthreads();
    }

    // lane groups cover disjoint j-sets for the same e-col -> combine.
    s0 += __shfl_xor(s0, 16); s0 += __shfl_xor(s0, 32);
    s1 += __shfl_xor(s1, 16); s1 += __shfl_xor(s1, 32);
    s2 += __shfl_xor(s2, 16); s2 += __shfl_xor(s2, 32);
    s3 += __shfl_xor(s3, 16); s3 += __shfl_xor(s3, 32);

    if (lane < 16) {
        Sout[(size_t)(e0 + lane) * NSPLIT + split]      = s0;
        Sout[(size_t)(e0 + 16 + lane) * NSPLIT + split] = s1;
        Sout[(size_t)(e0 + 32 + lane) * NSPLIT + split] = s2;
        Sout[(size_t)(e0 + 48 + lane) * NSPLIT + split] = s3;
    }
}

// One thread per row: combine split partials -> rowloss; LDS-reduce -> partial.
__global__ void finalize_kernel(const float* __restrict__ Sp,      // [K][NSPLIT]
                                const float* __restrict__ rowdot,  // [K]
                                float* __restrict__ partial) {     // [64]
    __shared__ float sm[256];
    const int row = blockIdx.x * 256 + threadIdx.x;

    const f32x4* sp = reinterpret_cast<const f32x4*>(Sp + (size_t)row * NSPLIT);
    float S = 0.0f;
#pragma unroll
    for (int q = 0; q < NSPLIT / 4; ++q) {
        f32x4 v = sp[q];
        S += (v[0] + v[1]) + (v[2] + v[3]);
    }
    const float LN2 = 0.6931471805599453f;
    float loss = LN2 * __builtin_amdgcn_logf(S) - rowdot[row];  // v_log_f32 = log2

    sm[threadIdx.x] = loss;
    __syncthreads();
    for (int off = 128; off > 0; off >>= 1) {
        if (threadIdx.x < off) sm[threadIdx.x] += sm[threadIdx.x + off];
        __syncthreads();
    }
    if (threadIdx.x == 0)
        partial[blockIdx.x] = sm[0];
}

__global__ void reduce_kernel(const float* __restrict__ partial, float* __restrict__ out) {
    const int lane = threadIdx.x;   // 64 threads
    float v = partial[lane];
#pragma unroll
    for (int off = 32; off > 0; off >>= 1)
        v += __shfl_xor(v, off);
    if (lane == 0)
        out[0] = v / (float)K_DIM;
}

extern "C" void kernel_launch(void* const* d_in, const int* in_sizes, int n_in,
                              void* d_out, int out_size, void* d_ws, size_t ws_size,
                              hipStream_t stream) {
    const float* parts   = (const float*)d_in[0];
    const float* centers = (const float*)d_in[1];
    float* out = (float*)d_out;

    char* ws = (char*)d_ws;
    unsigned* pb8  = (unsigned*)ws;                            // 2 MB
    unsigned* cbI8 = (unsigned*)(ws + 2u * 1024 * 1024);       // 2 MB
    float*  Sp  = (float*)(ws + 4u * 1024 * 1024);             // 2 MB (K*32 f32)
    float*  rowdot  = Sp + (size_t)K_DIM * NSPLIT;             // 64 KB
    float*  partial = rowdot + K_DIM;                          // 256 B

    const int n4 = (K_DIM * D_DIM) / 4;
    convert_kernel<<<n4 / 256, 256, 0, stream>>>(parts, centers, pb8, cbI8, rowdot);
    lse_gemm_kernel<<<(K_DIM / 256) * NSPLIT, 256, 0, stream>>>(
        (const unsigned char*)pb8, (const unsigned char*)cbI8, Sp);
    finalize_kernel<<<K_DIM / 256, 256, 0, stream>>>(Sp, rowdot, partial);
    reduce_kernel<<<1, 64, 0, stream>>>(partial, out);
}

// Round 21
// 52.475 us; speedup vs baseline: 1.1144x; 1.0555x over previous
//
#include <hip/hip_runtime.h>
#include <hip/hip_bf16.h>

// SCE loss: loss = mean_e [ logsumexp_j(parts[e].centers[j]) - parts[e].centers[e] ]
// K=16384, D=128, fp32 inputs, scalar fp32 output.
//
//  k1: fp32 -> fp8(e4m3) convert + fused fp32 diagonal dot. parts -> pb8
//      [K][128] row-major (scaled by log2 e); centers -> cbI8 fragment-
//      interleaved [K/16][4][16][32] so LDS A-reads are lane-contiguous.
//  k2: sum-of-exp2 GEMM, mfma_scale_f32_16x16x128_f8f6f4 (unit scales):
//      one instruction = full K=128, acc = 4 regs, 8 independent MFMAs/tile.
//      R21: per-SIMD ledger showed 26k/111k cyc idle = block-granularity
//      overhead (8 barriers/block x 8 sequential generations/CU). Fix:
//      NSPLIT=16 -> 1024 blocks = ONE generation/CU (no generation-switch
//      drains); 4-tile rounds (LDS 2x4x4KB=32KB, sequential staging keeps
//      1 staged reg live) -> barrier per 4 tiles.
//  k3: finalize: 1 thread/row: sum 16 split partials + rowdot -> rowloss;
//      LDS-reduce -> 64 block partials (no atomics).
//  k4: reduce 64 partials -> mean.

#define K_DIM 16384
#define D_DIM 128
#define NSPLIT 16
#define COLS_PER_SPLIT (K_DIM / NSPLIT)          // 1024
#define TILES_PER_SPLIT (COLS_PER_SPLIT / 32)    // 32
#define RTILES 4
#define NROUND (TILES_PER_SPLIT / RTILES)        // 8

typedef __attribute__((ext_vector_type(8)))  int    i32x8;
typedef __attribute__((ext_vector_type(4)))  float  f32x4;
typedef __attribute__((ext_vector_type(2)))  float  f32x2;

__device__ __forceinline__ unsigned pack_fp8x4(float f0, float f1, float f2, float f3) {
    int r = 0;
    r = __builtin_amdgcn_cvt_pk_fp8_f32(f0, f1, r, false);  // bytes 0,1
    r = __builtin_amdgcn_cvt_pk_fp8_f32(f2, f3, r, true);   // bytes 2,3
    return (unsigned)r;
}

__global__ void convert_kernel(const float* __restrict__ parts,
                               const float* __restrict__ centers,
                               unsigned* __restrict__ pb8,    // [K][128] row-major
                               unsigned* __restrict__ cbI8,   // [K/16][4][16][32]
                               float* __restrict__ rowdot) {  // [K]
    const float LOG2E = 1.4426950408889634f;
    int i = blockIdx.x * blockDim.x + threadIdx.x;   // one thread per 4 elems
    const int lane = threadIdx.x & 63;

    f32x4 p = reinterpret_cast<const f32x4*>(parts)[i];
    f32x4 c = reinterpret_cast<const f32x4*>(centers)[i];
    pb8[i] = pack_fp8x4(p[0] * LOG2E, p[1] * LOG2E, p[2] * LOG2E, p[3] * LOG2E);

    const int e0v = i * 4;
    const int j   = e0v >> 7;        // row
    const int d0  = e0v & 127;       // col
    // cbI8: byte (j,d) -> ((jb*4 + c)*16 + jr)*32 + b ; c=d>>5, b=d&31
    const int idx = (((j >> 4) * 4 + (d0 >> 5)) * 16 + (j & 15)) * 8 + ((d0 & 31) >> 2);
    cbI8[idx] = pack_fp8x4(c[0], c[1], c[2], c[3]);

    // fused fp32 diagonal dot: 32 consecutive threads own one row
    float dd = p[0] * c[0] + p[1] * c[1] + p[2] * c[2] + p[3] * c[3];
#pragma unroll
    for (int off = 16; off > 0; off >>= 1)
        dd += __shfl_xor(dd, off);       // stays within each 32-lane half
    if ((lane & 31) == 0)
        rowdot[j] = dd;
}

// Partial sum-of-exp2 (base-2). One wave: 64 e-rows x one split.
// 16x16x128 MX-fp8 MFMA; A-tiles (4KB) staged in LDS, lane-contiguous;
// 4-tile rounds, 1 barrier/round; 1024 blocks = single generation/CU.
__launch_bounds__(256, 4)
__global__ void lse_gemm_kernel(const unsigned char* __restrict__ P8,   // pb8 [K][128]
                                const unsigned char* __restrict__ CI8,  // cbI8
                                float* __restrict__ Sout) {             // [K][NSPLIT]
    // 2 pairs x 4 tiles x 4KB = 32KB
    __shared__ __attribute__((aligned(128))) unsigned char As[2][RTILES][4096];

    const int bid   = blockIdx.x;                 // 1024 blocks
    const int xcd    = bid & 7;                   // XCD-aware remap
    const int k      = bid >> 3;                  // 0..127
    const int split  = xcd * 2 + (k & 1);         // 0..15
    const int rowblk = k >> 1;                    // 0..63
    const int tid   = threadIdx.x;
    const int lane  = tid & 63;
    const int w     = tid >> 6;
    const int l15   = lane & 15;
    const int lg    = lane >> 4;                  // lane group 0..3
    const int rowgrp = rowblk * 4 + w;            // 0..255
    const int e0    = rowgrp * 64;

    // B fragments (parts rows): eblock eb, lane -> col e0+eb*16+l15,
    // k-bytes lg*32..+31 of that row. 4 x i32x8 = 32 VGPR.
    i32x8 bf[4];
#pragma unroll
    for (int eb = 0; eb < 4; ++eb) {
        const unsigned char* pr = P8 + (size_t)(e0 + eb * 16 + l15) * D_DIM + lg * 32;
#pragma unroll
        for (int q = 0; q < 4; ++q) {
            bf[eb][q]     = reinterpret_cast<const int*>(pr)[q];
            bf[eb][q + 4] = reinterpret_cast<const int*>(pr + 16)[q];
        }
    }

    const int j0 = split * COLS_PER_SPLIT;
    // Staging: thread tid copies 16B, linear (cbI8 tile is 4KB contiguous).
    const unsigned char* gsrc = CI8 + (size_t)(j0 >> 4) * 2048 + tid * 16;
    // A-read offset within a 2KB jblock: lane -> row l15, k-chunk lg.
    const int ra = l15 * 32 + lg * 512;

    const f32x4 zc = {};
    float s0 = 0.f, s1 = 0.f, s2 = 0.f, s3 = 0.f;

    auto esum4 = [&](const f32x4& acc) -> float {
        f32x2 v = {__builtin_amdgcn_exp2f(acc[0]), __builtin_amdgcn_exp2f(acc[1])};
        f32x2 u = {__builtin_amdgcn_exp2f(acc[2]), __builtin_amdgcn_exp2f(acc[3])};
        v += u;
        return v[0] + v[1];
    };

    auto do_tile = [&](const unsigned char* base) {
        i32x8 aA, aB;                 // jblock 0 and 1 fragments
#pragma unroll
        for (int q = 0; q < 4; ++q) {
            aA[q]     = reinterpret_cast<const int*>(base + ra)[q];
            aA[q + 4] = reinterpret_cast<const int*>(base + ra + 16)[q];
            aB[q]     = reinterpret_cast<const int*>(base + 2048 + ra)[q];
            aB[q + 4] = reinterpret_cast<const int*>(base + 2048 + ra + 16)[q];
        }
        f32x4 acc;
        acc = __builtin_amdgcn_mfma_scale_f32_16x16x128_f8f6f4(aA, bf[0], zc, 0, 0, 0, 0x7F, 0, 0x7F);
        s0 += esum4(acc);
        acc = __builtin_amdgcn_mfma_scale_f32_16x16x128_f8f6f4(aB, bf[0], zc, 0, 0, 0, 0x7F, 0, 0x7F);
        s0 += esum4(acc);
        acc = __builtin_amdgcn_mfma_scale_f32_16x16x128_f8f6f4(aA, bf[1], zc, 0, 0, 0, 0x7F, 0, 0x7F);
        s1 += esum4(acc);
        acc = __builtin_amdgcn_mfma_scale_f32_16x16x128_f8f6f4(aB, bf[1], zc, 0, 0, 0, 0x7F, 0, 0x7F);
        s1 += esum4(acc);
        acc = __builtin_amdgcn_mfma_scale_f32_16x16x128_f8f6f4(aA, bf[2], zc, 0, 0, 0, 0x7F, 0, 0x7F);
        s2 += esum4(acc);
        acc = __builtin_amdgcn_mfma_scale_f32_16x16x128_f8f6f4(aB, bf[2], zc, 0, 0, 0, 0x7F, 0, 0x7F);
        s2 += esum4(acc);
        acc = __builtin_amdgcn_mfma_scale_f32_16x16x128_f8f6f4(aA, bf[3], zc, 0, 0, 0, 0x7F, 0, 0x7F);
        s3 += esum4(acc);
        acc = __builtin_amdgcn_mfma_scale_f32_16x16x128_f8f6f4(aB, bf[3], zc, 0, 0, 0, 0x7F, 0, 0x7F);
        s3 += esum4(acc);
    };

    // prologue: stage tiles 0..3 into pair 0 (16B/thread/tile, sequential)
#pragma unroll
    for (int i = 0; i < RTILES; ++i) {
        int4 rg = *reinterpret_cast<const int4*>(gsrc + (size_t)i * 4096);
        *reinterpret_cast<int4*>(&As[0][i][tid * 16]) = rg;
    }
    __syncthreads();

    for (int r = 0; r < NROUND; ++r) {
        const int cur = r & 1;
        const int nxt = cur ^ 1;
        const bool pf = (r + 1 < NROUND);

#pragma unroll
        for (int i = 0; i < RTILES; ++i) {
            int4 rg;
            if (pf) rg = *reinterpret_cast<const int4*>(
                gsrc + (size_t)(RTILES * (r + 1) + i) * 4096);
            do_tile(&As[cur][i][0]);
            if (pf) *reinterpret_cast<int4*>(&As[nxt][i][tid * 16]) = rg;
        }
        __syncthreads();
    }

    // lane groups cover disjoint j-sets for the same e-col -> combine.
    s0 += __shfl_xor(s0, 16); s0 += __shfl_xor(s0, 32);
    s1 += __shfl_xor(s1, 16); s1 += __shfl_xor(s1, 32);
    s2 += __shfl_xor(s2, 16); s2 += __shfl_xor(s2, 32);
    s3 += __shfl_xor(s3, 16); s3 += __shfl_xor(s3, 32);

    if (lane < 16) {
        Sout[(size_t)(e0 + lane) * NSPLIT + split]      = s0;
        Sout[(size_t)(e0 + 16 + lane) * NSPLIT + split] = s1;
        Sout[(size_t)(e0 + 32 + lane) * NSPLIT + split] = s2;
        Sout[(size_t)(e0 + 48 + lane) * NSPLIT + split] = s3;
    }
}

// One thread per row: combine split partials -> rowloss; LDS-reduce -> partial.
__global__ void finalize_kernel(const float* __restrict__ Sp,      // [K][NSPLIT]
                                const float* __restrict__ rowdot,  // [K]
                                float* __restrict__ partial) {     // [64]
    __shared__ float sm[256];
    const int row = blockIdx.x * 256 + threadIdx.x;

    const f32x4* sp = reinterpret_cast<const f32x4*>(Sp + (size_t)row * NSPLIT);
    float S = 0.0f;
#pragma unroll
    for (int q = 0; q < NSPLIT / 4; ++q) {
        f32x4 v = sp[q];
        S += (v[0] + v[1]) + (v[2] + v[3]);
    }
    const float LN2 = 0.6931471805599453f;
    float loss = LN2 * __builtin_amdgcn_logf(S) - rowdot[row];  // v_log_f32 = log2

    sm[threadIdx.x] = loss;
    __syncthreads();
    for (int off = 128; off > 0; off >>= 1) {
        if (threadIdx.x < off) sm[threadIdx.x] += sm[threadIdx.x + off];
        __syncthreads();
    }
    if (threadIdx.x == 0)
        partial[blockIdx.x] = sm[0];
}

__global__ void reduce_kernel(const float* __restrict__ partial, float* __restrict__ out) {
    const int lane = threadIdx.x;   // 64 threads
    float v = partial[lane];
#pragma unroll
    for (int off = 32; off > 0; off >>= 1)
        v += __shfl_xor(v, off);
    if (lane == 0)
        out[0] = v / (float)K_DIM;
}

extern "C" void kernel_launch(void* const* d_in, const int* in_sizes, int n_in,
                              void* d_out, int out_size, void* d_ws, size_t ws_size,
                              hipStream_t stream) {
    const float* parts   = (const float*)d_in[0];
    const float* centers = (const float*)d_in[1];
    float* out = (float*)d_out;

    char* ws = (char*)d_ws;
    unsigned* pb8  = (unsigned*)ws;                            // 2 MB
    unsigned* cbI8 = (unsigned*)(ws + 2u * 1024 * 1024);       // 2 MB
    float*  Sp  = (float*)(ws + 4u * 1024 * 1024);             // 1 MB (K*16 f32)
    float*  rowdot  = Sp + (size_t)K_DIM * NSPLIT;             // 64 KB
    float*  partial = rowdot + K_DIM;                          // 256 B

    const int n4 = (K_DIM * D_DIM) / 4;
    convert_kernel<<<n4 / 256, 256, 0, stream>>>(parts, centers, pb8, cbI8, rowdot);
    lse_gemm_kernel<<<(K_DIM / 256) * NSPLIT, 256, 0, stream>>>(
        (const unsigned char*)pb8, (const unsigned char*)cbI8, Sp);
    finalize_kernel<<<K_DIM / 256, 256, 0, stream>>>(Sp, rowdot, partial);
    reduce_kernel<<<1, 64, 0, stream>>>(partial, out);
}